// Round 4
// baseline (451.954 us; speedup 1.0000x reference)
//
#include <hip/hip_runtime.h>

#define Bb 128
#define Tt 1024
#define Dd 512
#define Vv 128
#define Ll 128
#define EPSF 1e-7f
#define PADK 72
#define NEGF -1e30f

typedef float f4 __attribute__((ext_vector_type(4)));
typedef short s8 __attribute__((ext_vector_type(8)));
typedef float f32x4 __attribute__((ext_vector_type(4)));

__device__ inline unsigned int f2bf(float f) {
    unsigned int u = __float_as_uint(f);
    return (u + 0x7fffu + ((u >> 16) & 1u)) >> 16;  // RNE bf16 (no NaN inputs)
}

// logaddexp via hw v_exp_f32/v_log_f32 -- used only in the one-time readout.
__device__ inline float lae2(float x, float y) {
    float m = fmaxf(x, y);
    float d = fminf(x, y) - m;                       // <= 0 (0 when both NEG)
    return m + __logf(1.f + __expf(d));
}

// wave-wide shift-up-by-1 (lane i reads lane i-1, lane0 -> 0): DPP wave_shr:1
__device__ inline float dpp_shr1(float v) {
    return __int_as_float(__builtin_amdgcn_update_dpp(
        0, __float_as_int(v), 0x138, 0xf, 0xf, false));
}
__device__ inline int dpp_shr1_i(int v) {
    return __builtin_amdgcn_update_dpp(0, v, 0x138, 0xf, 0xf, false);
}

// Prep: W [512,128] f32 -> Wt [v][k] bf16 (B^T layout for MFMA B-operand)
__global__ void wt_kernel(const float* __restrict__ W, unsigned short* __restrict__ Wt) {
    int idx = blockIdx.x * 256 + threadIdx.x;   // 65536
    int v = idx >> 9, k = idx & 511;
    Wt[idx] = (unsigned short)f2bf(W[k * Vv + v]);
}

// Fused GEMM (bf16 MFMA) + bias + softmax.
// Output is TRANSPOSED: LP_T[b][v][t] = softmax_v + EPS, so the CTC kernel's
// per-lane column reads become sequential streams.
__global__ __launch_bounds__(256) void gemm_softmax(
    const float* __restrict__ x, const unsigned short* __restrict__ Wt,
    const float* __restrict__ bias, float* __restrict__ LP)
{
    __shared__ float lds[128 * 128];           // 64 KB: staging tiles, then probs in epilogue
    __shared__ float invs[128];                // per-row 1/sum for the transposed store pass
    unsigned short* Al = (unsigned short*)lds;         // [128][PADK] bf16
    unsigned short* Bl = Al + 128 * PADK;              // [128][PADK] bf16 (v-major)

    const int tid = threadIdx.x;
    const int wave = tid >> 6, lane = tid & 63;
    const int lm = lane & 15, lq = lane >> 4;
    const int wm = (wave >> 1) << 6, wn = (wave & 1) << 6;
    const long row0 = (long)blockIdx.x << 7;

    f32x4 acc[4][4];
    #pragma unroll
    for (int i = 0; i < 4; i++)
        #pragma unroll
        for (int j = 0; j < 4; j++)
            acc[i][j] = (f32x4){0.f, 0.f, 0.f, 0.f};

    for (int k0 = 0; k0 < Dd; k0 += 64) {
        __syncthreads();
        // stage A: 128 rows x 64 k, f32 -> bf16  (2048 float4)
        #pragma unroll
        for (int i = 0; i < 8; i++) {
            int idx = tid + (i << 8);
            int r = idx >> 4, c4 = idx & 15;
            f4 v = *(const f4*)(x + (row0 + r) * Dd + k0 + (c4 << 2));
            unsigned long long q =
                (unsigned long long)(f2bf(v.x) | (f2bf(v.y) << 16)) |
                ((unsigned long long)(f2bf(v.z) | (f2bf(v.w) << 16)) << 32);
            *(unsigned long long*)(Al + r * PADK + (c4 << 2)) = q;
        }
        // stage B: 128 v-rows x 8 chunks of 8 shorts
        #pragma unroll
        for (int i = 0; i < 4; i++) {
            int idx = tid + (i << 8);
            int vr = idx >> 3, c = idx & 7;
            f4 w = *(const f4*)(Wt + vr * 512 + k0 + (c << 3));
            *(f4*)(Bl + vr * PADK + (c << 3)) = w;
        }
        __syncthreads();
        #pragma unroll
        for (int kk = 0; kk < 64; kk += 32) {
            s8 af[4], bfr[4];
            #pragma unroll
            for (int mi = 0; mi < 4; mi++)
                af[mi] = *(const s8*)(Al + (wm + (mi << 4) + lm) * PADK + kk + (lq << 3));
            #pragma unroll
            for (int ni = 0; ni < 4; ni++)
                bfr[ni] = *(const s8*)(Bl + (wn + (ni << 4) + lm) * PADK + kk + (lq << 3));
            #pragma unroll
            for (int mi = 0; mi < 4; mi++)
                #pragma unroll
                for (int ni = 0; ni < 4; ni++)
                    acc[mi][ni] = __builtin_amdgcn_mfma_f32_16x16x32_bf16(
                        af[mi], bfr[ni], acc[mi][ni], 0, 0, 0);
        }
    }
    __syncthreads();
    // write logits+bias to swizzled LDS (chunk rotation, bijective per row)
    #pragma unroll
    for (int mi = 0; mi < 4; mi++) {
        #pragma unroll
        for (int ni = 0; ni < 4; ni++) {
            int col = wn + (ni << 4) + lm;
            float bv = bias[col];
            #pragma unroll
            for (int r = 0; r < 4; r++) {
                int row = wm + (mi << 4) + (lq << 2) + r;
                int word = (row << 7) + ((((col >> 2) + row) & 31) << 2) + (col & 3);
                lds[word] = acc[mi][ni][r] + bv;
            }
        }
    }
    __syncthreads();
    // pass 1+2: per-row max, exp, sum (128 threads, one per t-row)
    if (tid < 128) {
        int row = tid;
        float m = -1e30f;
        #pragma unroll
        for (int c = 0; c < 32; c++) {
            int word = (row << 7) + (((c + row) & 31) << 2);
            f4 v = *(const f4*)(lds + word);
            m = fmaxf(m, fmaxf(fmaxf(v.x, v.y), fmaxf(v.z, v.w)));
        }
        float s = 0.f;
        #pragma unroll
        for (int c = 0; c < 32; c++) {
            int word = (row << 7) + (((c + row) & 31) << 2);
            f4 v = *(f4*)(lds + word);
            v.x = __expf(v.x - m); v.y = __expf(v.y - m);
            v.z = __expf(v.z - m); v.w = __expf(v.w - m);
            s += v.x + v.y + v.z + v.w;
            *(f4*)(lds + word) = v;
        }
        invs[row] = 1.f / s;
    }
    __syncthreads();
    // pass 3: transposed store. thread -> (v = tid>>1, t-half = tid&1);
    // reads column v across rows (rotation keeps banks 2-way), stores
    // 64 consecutive t per thread (L2 write-combines the 16B chunks).
    {
        const int v = tid >> 1, h = tid & 1;
        const int bidx = blockIdx.x >> 3;           // example
        const int tbase = (blockIdx.x & 7) << 7;    // t-offset within example
        float* dst = LP + ((long)bidx * Vv + v) * Tt + tbase + (h << 6);
        const int c0w = v >> 2, r0 = v & 3;
        #pragma unroll
        for (int j4 = 0; j4 < 16; j4++) {
            f4 o;
            #pragma unroll
            for (int jj = 0; jj < 4; jj++) {
                int t = (h << 6) + (j4 << 2) + jj;
                int word = (t << 7) + (((c0w + t) & 31) << 2) + r0;
                o[jj] = fmaf(lds[word], invs[t], EPSF);
            }
            *(f4*)(dst + (j4 << 2)) = o;
        }
    }
}

// CTC forward DP, LINEAR domain with per-lane power-of-2 anchors.
// One wave per example; lane i owns states 4i..4i+3 as u_s ~= alpha_s / 2^anc.
// P is TRANSPOSED [b][v][t]: each lane reads 3 sequential streams, DEPTH-2
// register pipeline (3 rotating buffer sets, macro-rotated roles -> zero
// copies, all-static f4 indexing) so ~1000cy of L3 latency is covered.
// Per step: one DPP wave-shift feed, 7 adds, 6 muls; zero transcendentals.
// Rescale every 4 steps. Windows 0..15 (t<=255): full rescale with dead-lane
// anchor adoption. Windows 16..63: lean rescale -- all 257 states are
// provably live by t=255 (s->s+1 is always legal with p>=eps, so the
// reachability front advances >=1 state/step), so adoption and the live
// select are dead weight there.
__global__ __launch_bounds__(64) void ctc_kernel(
    const float* __restrict__ PT, const int* __restrict__ targets,
    const int* __restrict__ tlen, float* __restrict__ out)
{
    const int b = blockIdx.x;
    const int lane = threadIdx.x;
    const float* baseP = PT + (long)b * Vv * Tt;

    const int tgt0 = targets[(b << 7) + (lane << 1)];
    const int tgt1 = targets[(b << 7) + (lane << 1) + 1];
    int tp = __shfl_up(tgt1, 1);
    if (lane == 0) tp = -1;
    const bool mA = (tgt0 != tp);      // skip allowed into s=4i+1
    const bool mB = (tgt1 != tgt0);    // skip allowed into s=4i+3

    const float* pB = baseP + 127 * Tt;
    const float* p0 = baseP + (long)tgt0 * Tt;
    const float* p1 = baseP + (long)tgt1 * Tt;

    // t = 0: only s=0 (blank) and s=1 (first label) reachable
    float u0 = (lane == 0) ? pB[0] : 0.f;
    float u1 = (lane == 0) ? p0[0] : 0.f;
    float u2 = 0.f, u3 = 0.f, u4 = 0.f;
    int anc = 0;           // per-lane anchor: alpha = u * 2^anc
    float fprev = 1.f;     // 2^(anc_{lane-1} - anc)

    // three rotating buffer sets, 4 f4 per stream each
    f4 Xb[4], Xs[4], Xt[4], Yb[4], Ys[4], Yt[4], Zb[4], Zs[4], Zt[4];

#define LOADW(BUF, W) do {                                                  \
    int tn_ = ((W) < 63 ? (W) : 63) << 4;                                   \
    _Pragma("unroll")                                                       \
    for (int q = 0; q < 4; q++) {                                           \
        BUF##b[q] = *(const f4*)(pB + tn_ + (q << 2));                      \
        BUF##s[q] = *(const f4*)(p0 + tn_ + (q << 2));                      \
        BUF##t[q] = *(const f4*)(p1 + tn_ + (q << 2));                      \
    } } while (0)

#define DOSTEP(BUF, i) do {                                                 \
    float lb = BUF##b[(i) >> 2][(i) & 3];                                   \
    float l0 = BUF##s[(i) >> 2][(i) & 3];                                   \
    float l1 = BUF##t[(i) >> 2][(i) & 3];                                   \
    float us = dpp_shr1(u3) * fprev;              /* lane0 -> 0 */          \
    float n0 = (u0 + us) * lb;                                              \
    float n1 = (u0 + u1 + (mA ? us : 0.f)) * l0;                            \
    float n2 = (u1 + u2) * lb;                                              \
    float n3 = (u2 + u3 + (mB ? u1 : 0.f)) * l1;                            \
    float n4 = (u3 + u4) * lb;                                              \
    u0 = n0; u1 = n1; u2 = n2; u3 = n3; u4 = n4; } while (0)

#define RESCALE(ADOPT) do {                                                 \
    float umax = fmaxf(fmaxf(fmaxf(u0, u1), fmaxf(u2, u3)), u4);            \
    int e = (int)((__float_as_uint(umax) >> 23) & 0xffu) - 126;             \
    float sc = __uint_as_float((unsigned)(127 - e) << 23);   /* 2^-e */     \
    u0 *= sc; u1 *= sc; u2 *= sc; u3 *= sc; u4 *= sc;    /* dead: 0->0 */   \
    if (ADOPT) {                                                            \
        bool live = umax > 0.f;                                             \
        anc = live ? (anc + e) : anc;                                       \
        _Pragma("unroll")                                                   \
        for (int r_ = 0; r_ < 3; r_++) {                                    \
            int cp_ = dpp_shr1_i(anc);                                      \
            anc = live ? anc : cp_;                                         \
        }                                                                   \
    } else {                                                                \
        anc += e;                                                           \
    }                                                                       \
    int cp = dpp_shr1_i(anc);                                               \
    int d_ = cp - anc;                                                      \
    d_ = d_ > 96 ? 96 : d_;          /* cap: feed stays finite */           \
    fprev = (d_ < -126) ? 0.f                                               \
           : __uint_as_float((unsigned)((d_ + 127) << 23)); } while (0)

#define WINDOW(CUR, N2, W, ADOPT, ISTART) do {                              \
    LOADW(N2, (W) + 2);                                                     \
    _Pragma("unroll")                                                       \
    for (int i = ISTART; i < 16; i++) {                                     \
        DOSTEP(CUR, i);                                                     \
        if ((i & 3) == 3) RESCALE(ADOPT);                                   \
    } } while (0)

    LOADW(X, 0);
    LOADW(Y, 1);
    WINDOW(X, Z, 0, true, 1);                    // win0 (t=1..15), loads win2
    for (int g = 0; g < 5; g++) {                // w = 1..15, adoption phase
        int w = 1 + 3 * g;
        WINDOW(Y, X, w,     true, 0);
        WINDOW(Z, Y, w + 1, true, 0);
        WINDOW(X, Z, w + 2, true, 0);
    }
    for (int g = 0; g < 16; g++) {               // w = 16..63, lean phase
        int w = 16 + 3 * g;
        WINDOW(Y, X, w,     false, 0);
        WINDOW(Z, Y, w + 1, false, 0);
        WINDOW(X, Z, w + 2, false, 0);
    }

    // readout: convert lane states to log domain once, then exact lae2
    __shared__ float af[257];
    const float LN2 = 0.69314718056f;
    float fa = (float)anc;
    af[(lane << 2) + 0] = u0 > 0.f ? (fa + log2f(u0)) * LN2 : NEGF;
    af[(lane << 2) + 1] = u1 > 0.f ? (fa + log2f(u1)) * LN2 : NEGF;
    af[(lane << 2) + 2] = u2 > 0.f ? (fa + log2f(u2)) * LN2 : NEGF;
    af[(lane << 2) + 3] = u3 > 0.f ? (fa + log2f(u3)) * LN2 : NEGF;
    if (lane == 63) af[256] = u4 > 0.f ? (fa + log2f(u4)) * LN2 : NEGF;
    __syncthreads();
    if (lane == 0) {
        int len = tlen[b];
        float loss = -lae2(af[2 * len], af[2 * len - 1]);
        atomicAdd(out, loss);
    }
}

extern "C" void kernel_launch(void* const* d_in, const int* in_sizes, int n_in,
                              void* d_out, int out_size, void* d_ws, size_t ws_size,
                              hipStream_t stream) {
    const float* x       = (const float*)d_in[0];
    const float* W       = (const float*)d_in[1];
    const float* bias    = (const float*)d_in[2];
    const int*   targets = (const int*)d_in[3];
    const int*   tl      = (const int*)d_in[4];
    float* out = (float*)d_out;

    float* LP = (float*)d_ws;                                      // 64 MB transposed probs
    unsigned short* Wt = (unsigned short*)((char*)d_ws + (size_t)Bb * Tt * Vv * 4);

    (void)hipMemsetAsync(out, 0, sizeof(float), stream);
    wt_kernel<<<256, 256, 0, stream>>>(W, Wt);
    gemm_softmax<<<1024, 256, 0, stream>>>(x, Wt, bias, LP);
    ctc_kernel<<<Bb, 64, 0, stream>>>(LP, targets, tl, out);
}

// Round 5
// 434.120 us; speedup vs baseline: 1.0411x; 1.0411x over previous
//
#include <hip/hip_runtime.h>

#define Bb 128
#define Tt 1024
#define Dd 512
#define Vv 128
#define Ll 128
#define EPSF 1e-7f
#define PADK 72
#define NEGF -1e30f

typedef float f4 __attribute__((ext_vector_type(4)));
typedef short s8 __attribute__((ext_vector_type(8)));
typedef float f32x4 __attribute__((ext_vector_type(4)));

__device__ inline unsigned int f2bf(float f) {
    unsigned int u = __float_as_uint(f);
    return (u + 0x7fffu + ((u >> 16) & 1u)) >> 16;  // RNE bf16 (no NaN inputs)
}

// logaddexp via hw v_exp_f32/v_log_f32 -- used only in the one-time readout.
__device__ inline float lae2(float x, float y) {
    float m = fmaxf(x, y);
    float d = fminf(x, y) - m;                       // <= 0 (0 when both NEG)
    return m + __logf(1.f + __expf(d));
}

// wave-wide shift-up-by-1 (lane i reads lane i-1, lane0 -> 0): DPP wave_shr:1
__device__ inline float dpp_shr1(float v) {
    return __int_as_float(__builtin_amdgcn_update_dpp(
        0, __float_as_int(v), 0x138, 0xf, 0xf, false));
}
__device__ inline int dpp_shr1_i(int v) {
    return __builtin_amdgcn_update_dpp(0, v, 0x138, 0xf, 0xf, false);
}

// Prep: W [512,128] f32 -> Wt [v][k] bf16 (B^T layout for MFMA B-operand)
__global__ void wt_kernel(const float* __restrict__ W, unsigned short* __restrict__ Wt) {
    int idx = blockIdx.x * 256 + threadIdx.x;   // 65536
    int v = idx >> 9, k = idx & 511;
    Wt[idx] = (unsigned short)f2bf(W[k * Vv + v]);
}

// Fused GEMM (bf16 MFMA) + bias + softmax.
// Output TRANSPOSED: LP_T[b][v][t] = softmax_v + EPS.
// LDS prob layout is XOR-swizzled: word(t,v) = t*128 + ((v>>2 ^ (t>>2)&7)<<2)
// + (v&3) -- row passes stay conflict-balanced via rotated chunk iteration,
// column reads (pass 3) drop from 16-way to ~4-way conflicts, and the global
// store pass is remapped so each half-wave writes one v-row's contiguous
// 512 B (fully covered lines; the R3 16B-scatter cost gemm ~46 us).
__global__ __launch_bounds__(256) void gemm_softmax(
    const float* __restrict__ x, const unsigned short* __restrict__ Wt,
    const float* __restrict__ bias, float* __restrict__ LP)
{
    __shared__ float lds[128 * 128];           // 64 KB: staging tiles, then probs in epilogue
    __shared__ __align__(16) float invs[128];  // per-row 1/sum for the transposed store pass
    unsigned short* Al = (unsigned short*)lds;         // [128][PADK] bf16
    unsigned short* Bl = Al + 128 * PADK;              // [128][PADK] bf16 (v-major)

    const int tid = threadIdx.x;
    const int wave = tid >> 6, lane = tid & 63;
    const int lm = lane & 15, lq = lane >> 4;
    const int wm = (wave >> 1) << 6, wn = (wave & 1) << 6;
    const long row0 = (long)blockIdx.x << 7;

    f32x4 acc[4][4];
    #pragma unroll
    for (int i = 0; i < 4; i++)
        #pragma unroll
        for (int j = 0; j < 4; j++)
            acc[i][j] = (f32x4){0.f, 0.f, 0.f, 0.f};

    for (int k0 = 0; k0 < Dd; k0 += 64) {
        __syncthreads();
        // stage A: 128 rows x 64 k, f32 -> bf16  (2048 float4)
        #pragma unroll
        for (int i = 0; i < 8; i++) {
            int idx = tid + (i << 8);
            int r = idx >> 4, c4 = idx & 15;
            f4 v = *(const f4*)(x + (row0 + r) * Dd + k0 + (c4 << 2));
            unsigned long long q =
                (unsigned long long)(f2bf(v.x) | (f2bf(v.y) << 16)) |
                ((unsigned long long)(f2bf(v.z) | (f2bf(v.w) << 16)) << 32);
            *(unsigned long long*)(Al + r * PADK + (c4 << 2)) = q;
        }
        // stage B: 128 v-rows x 8 chunks of 8 shorts
        #pragma unroll
        for (int i = 0; i < 4; i++) {
            int idx = tid + (i << 8);
            int vr = idx >> 3, c = idx & 7;
            f4 w = *(const f4*)(Wt + vr * 512 + k0 + (c << 3));
            *(f4*)(Bl + vr * PADK + (c << 3)) = w;
        }
        __syncthreads();
        #pragma unroll
        for (int kk = 0; kk < 64; kk += 32) {
            s8 af[4], bfr[4];
            #pragma unroll
            for (int mi = 0; mi < 4; mi++)
                af[mi] = *(const s8*)(Al + (wm + (mi << 4) + lm) * PADK + kk + (lq << 3));
            #pragma unroll
            for (int ni = 0; ni < 4; ni++)
                bfr[ni] = *(const s8*)(Bl + (wn + (ni << 4) + lm) * PADK + kk + (lq << 3));
            #pragma unroll
            for (int mi = 0; mi < 4; mi++)
                #pragma unroll
                for (int ni = 0; ni < 4; ni++)
                    acc[mi][ni] = __builtin_amdgcn_mfma_f32_16x16x32_bf16(
                        af[mi], bfr[ni], acc[mi][ni], 0, 0, 0);
        }
    }
    __syncthreads();
    // write logits+bias to XOR-swizzled LDS: word(t,v) (bijective per row)
    #pragma unroll
    for (int mi = 0; mi < 4; mi++) {
        #pragma unroll
        for (int ni = 0; ni < 4; ni++) {
            int col = wn + (ni << 4) + lm;
            float bv = bias[col];
            #pragma unroll
            for (int r = 0; r < 4; r++) {
                int row = wm + (mi << 4) + (lq << 2) + r;
                int word = (row << 7) + ((((col >> 2) ^ ((row >> 2) & 7)) & 31) << 2) + (col & 3);
                lds[word] = acc[mi][ni][r] + bv;
            }
        }
    }
    __syncthreads();
    // pass 1+2: per-row max, exp, sum (128 threads, one per t-row); chunk
    // iteration rotated by row so bank quads stay spread across lanes.
    if (tid < 128) {
        int row = tid;
        float m = -1e30f;
        #pragma unroll
        for (int cc = 0; cc < 32; cc++) {
            int word = (row << 7) + (((cc + row) & 31) << 2);
            f4 v = *(const f4*)(lds + word);
            m = fmaxf(m, fmaxf(fmaxf(v.x, v.y), fmaxf(v.z, v.w)));
        }
        float s = 0.f;
        #pragma unroll
        for (int cc = 0; cc < 32; cc++) {
            int word = (row << 7) + (((cc + row) & 31) << 2);
            f4 v = *(f4*)(lds + word);
            v.x = __expf(v.x - m); v.y = __expf(v.y - m);
            v.z = __expf(v.z - m); v.w = __expf(v.w - m);
            s += v.x + v.y + v.z + v.w;
            *(f4*)(lds + word) = v;
        }
        invs[row] = 1.f / s;
    }
    __syncthreads();
    // pass 3: coalesced transposed store. thread -> (l = tid&31 -> t = 4l,
    // g = tid>>5 -> v = 16g + jj). Per instruction each half-wave writes one
    // v-row's contiguous 512 B. LDS column reads ~4-way via the XOR swizzle.
    {
        const int l = tid & 31, g = tid >> 5;
        const int bidx = blockIdx.x >> 3;           // example
        const int tbase = (blockIdx.x & 7) << 7;    // t-offset within example
        const f4 iv = *(const f4*)(invs + (l << 2));    // inv[4l .. 4l+3]
        #pragma unroll
        for (int jj = 0; jj < 16; jj++) {
            const int v = (g << 4) + jj;
            const int swz = ((v >> 2) ^ (l & 7)) << 2;  // (t>>2)&7 == l&7
            const int r0 = v & 3;
            f4 o;
            #pragma unroll
            for (int r = 0; r < 4; r++) {
                int t = (l << 2) + r;
                o[r] = fmaf(lds[(t << 7) + swz + r0], iv[r], EPSF);
            }
            *(f4*)(LP + ((long)bidx * Vv + v) * Tt + tbase + (l << 2)) = o;
        }
    }
}

// CTC forward DP, LINEAR domain with per-lane power-of-2 anchors.
// One wave per example; lane i owns states 4i..4i+3 as u_s ~= alpha_s / 2^anc.
// P is TRANSPOSED [b][v][t]: each lane reads 3 sequential streams, depth-2
// register pipeline (3 rotating buffer sets). Per step: 13 VALU ops -- one
// DPP feed, selects folded into FMAs via precomputed fprevA (= mA?fprev:0,
// refreshed each rescale) and mBf (= mB?1:0). Rescale every 4 steps;
// windows 0..15 carry dead-lane anchor adoption, 16..63 lean (all 257
// states provably live by t=255: s->s+1 always legal with p>=eps).
__global__ __launch_bounds__(64) void ctc_kernel(
    const float* __restrict__ PT, const int* __restrict__ targets,
    const int* __restrict__ tlen, float* __restrict__ out)
{
    const int b = blockIdx.x;
    const int lane = threadIdx.x;
    const float* baseP = PT + (long)b * Vv * Tt;

    const int tgt0 = targets[(b << 7) + (lane << 1)];
    const int tgt1 = targets[(b << 7) + (lane << 1) + 1];
    int tp = __shfl_up(tgt1, 1);
    if (lane == 0) tp = -1;
    const bool mA = (tgt0 != tp);      // skip allowed into s=4i+1
    const bool mB = (tgt1 != tgt0);    // skip allowed into s=4i+3
    const float mBf = mB ? 1.f : 0.f;

    const float* pB = baseP + 127 * Tt;
    const float* p0 = baseP + (long)tgt0 * Tt;
    const float* p1 = baseP + (long)tgt1 * Tt;

    // t = 0: only s=0 (blank) and s=1 (first label) reachable
    float u0 = (lane == 0) ? pB[0] : 0.f;
    float u1 = (lane == 0) ? p0[0] : 0.f;
    float u2 = 0.f, u3 = 0.f, u4 = 0.f;
    int anc = 0;             // per-lane anchor: alpha = u * 2^anc
    float fprev = 1.f;       // 2^(anc_{lane-1} - anc)
    float fprevA = mA ? 1.f : 0.f;

    // three rotating buffer sets, 4 f4 per stream each
    f4 Xb[4], Xs[4], Xt[4], Yb[4], Ys[4], Yt[4], Zb[4], Zs[4], Zt[4];

#define LOADW(BUF, W) do {                                                  \
    int tn_ = ((W) < 63 ? (W) : 63) << 4;                                   \
    _Pragma("unroll")                                                       \
    for (int q = 0; q < 4; q++) {                                           \
        BUF##b[q] = *(const f4*)(pB + tn_ + (q << 2));                      \
        BUF##s[q] = *(const f4*)(p0 + tn_ + (q << 2));                      \
        BUF##t[q] = *(const f4*)(p1 + tn_ + (q << 2));                      \
    } } while (0)

#define DOSTEP(BUF, i) do {                                                 \
    float lb = BUF##b[(i) >> 2][(i) & 3];                                   \
    float l0 = BUF##s[(i) >> 2][(i) & 3];                                   \
    float l1 = BUF##t[(i) >> 2][(i) & 3];                                   \
    float s_ = dpp_shr1(u3);                      /* lane0 -> 0 */          \
    float t01 = u0 + u1;                                                    \
    float n0 = fmaf(s_, fprev,  u0) * lb;                                   \
    float n1 = fmaf(s_, fprevA, t01) * l0;                                  \
    float n2 = (u1 + u2) * lb;                                              \
    float n3 = fmaf(u1, mBf, u2 + u3) * l1;                                 \
    float n4 = (u3 + u4) * lb;                                              \
    u0 = n0; u1 = n1; u2 = n2; u3 = n3; u4 = n4; } while (0)

#define RESCALE(ADOPT) do {                                                 \
    float umax = fmaxf(fmaxf(fmaxf(u0, u1), fmaxf(u2, u3)), u4);            \
    int e = (int)((__float_as_uint(umax) >> 23) & 0xffu) - 126;             \
    float sc = __uint_as_float((unsigned)(127 - e) << 23);   /* 2^-e */     \
    u0 *= sc; u1 *= sc; u2 *= sc; u3 *= sc; u4 *= sc;    /* dead: 0->0 */   \
    if (ADOPT) {                                                            \
        bool live = umax > 0.f;                                             \
        anc = live ? (anc + e) : anc;                                       \
        _Pragma("unroll")                                                   \
        for (int r_ = 0; r_ < 3; r_++) {                                    \
            int cp_ = dpp_shr1_i(anc);                                      \
            anc = live ? anc : cp_;                                         \
        }                                                                   \
    } else {                                                                \
        anc += e;                                                           \
    }                                                                       \
    int cp = dpp_shr1_i(anc);                                               \
    int d_ = cp - anc;                                                      \
    d_ = d_ > 96 ? 96 : d_;          /* cap: feed stays finite */           \
    fprev = (d_ < -126) ? 0.f                                               \
           : __uint_as_float((unsigned)((d_ + 127) << 23));                 \
    fprevA = mA ? fprev : 0.f; } while (0)

#define WINDOW(CUR, N2, W, ADOPT, ISTART) do {                              \
    LOADW(N2, (W) + 2);                                                     \
    _Pragma("unroll")                                                       \
    for (int i = ISTART; i < 16; i++) {                                     \
        DOSTEP(CUR, i);                                                     \
        if ((i & 3) == 3) RESCALE(ADOPT);                                   \
    } } while (0)

    LOADW(X, 0);
    LOADW(Y, 1);
    WINDOW(X, Z, 0, true, 1);                    // win0 (t=1..15), loads win2
    for (int g = 0; g < 5; g++) {                // w = 1..15, adoption phase
        int w = 1 + 3 * g;
        WINDOW(Y, X, w,     true, 0);
        WINDOW(Z, Y, w + 1, true, 0);
        WINDOW(X, Z, w + 2, true, 0);
    }
    for (int g = 0; g < 16; g++) {               // w = 16..63, lean phase
        int w = 16 + 3 * g;
        WINDOW(Y, X, w,     false, 0);
        WINDOW(Z, Y, w + 1, false, 0);
        WINDOW(X, Z, w + 2, false, 0);
    }

    // readout: convert lane states to log domain once, then exact lae2
    __shared__ float af[257];
    const float LN2 = 0.69314718056f;
    float fa = (float)anc;
    af[(lane << 2) + 0] = u0 > 0.f ? (fa + log2f(u0)) * LN2 : NEGF;
    af[(lane << 2) + 1] = u1 > 0.f ? (fa + log2f(u1)) * LN2 : NEGF;
    af[(lane << 2) + 2] = u2 > 0.f ? (fa + log2f(u2)) * LN2 : NEGF;
    af[(lane << 2) + 3] = u3 > 0.f ? (fa + log2f(u3)) * LN2 : NEGF;
    if (lane == 63) af[256] = u4 > 0.f ? (fa + log2f(u4)) * LN2 : NEGF;
    __syncthreads();
    if (lane == 0) {
        int len = tlen[b];
        float loss = -lae2(af[2 * len], af[2 * len - 1]);
        atomicAdd(out, loss);
    }
}

extern "C" void kernel_launch(void* const* d_in, const int* in_sizes, int n_in,
                              void* d_out, int out_size, void* d_ws, size_t ws_size,
                              hipStream_t stream) {
    const float* x       = (const float*)d_in[0];
    const float* W       = (const float*)d_in[1];
    const float* bias    = (const float*)d_in[2];
    const int*   targets = (const int*)d_in[3];
    const int*   tl      = (const int*)d_in[4];
    float* out = (float*)d_out;

    float* LP = (float*)d_ws;                                      // 64 MB transposed probs
    unsigned short* Wt = (unsigned short*)((char*)d_ws + (size_t)Bb * Tt * Vv * 4);

    (void)hipMemsetAsync(out, 0, sizeof(float), stream);
    wt_kernel<<<256, 256, 0, stream>>>(W, Wt);
    gemm_softmax<<<1024, 256, 0, stream>>>(x, Wt, bias, LP);
    ctc_kernel<<<Bb, 64, 0, stream>>>(LP, targets, tl, out);
}